// Round 8
// baseline (200.458 us; speedup 1.0000x reference)
//
#include <hip/hip_runtime.h>
#include <hip/hip_bf16.h>

typedef unsigned short u16;
typedef unsigned int u32;
typedef __attribute__((ext_vector_type(8))) short short8;
typedef __attribute__((ext_vector_type(4))) short short4v;
typedef __attribute__((ext_vector_type(4))) float floatx4;

__device__ __forceinline__ float bf2f(u16 u) {
    union { u32 u; float f; } x; x.u = ((u32)u) << 16; return x.f;
}
__device__ __forceinline__ u16 f2bf(float f) {
    union { float f; u32 u; } x; x.f = f;
    u32 r = x.u + 0x7FFFu + ((x.u >> 16) & 1u);
    return (u16)(r >> 16);
}

// ---------------------------------------------------------------------------
// fp32 -> bf16 canonicalization of 7 tensors (pos stays fp32 now)
// ---------------------------------------------------------------------------
struct Cvt7 {
    const float* src[7];
    u16* dst[7];
    int pre[8];
};

__global__ __launch_bounds__(256) void convert7(Cvt7 a) {
    int total = a.pre[7];
    for (int g = blockIdx.x * 256 + threadIdx.x; g < total; g += gridDim.x * 256) {
        int seg = 0;
        while (a.pre[seg + 1] <= g) seg++;
        int off = g - a.pre[seg];
        float4 f = ((const float4*)a.src[seg])[off];
        short4v o;
        o[0] = (short)f2bf(f.x); o[1] = (short)f2bf(f.y);
        o[2] = (short)f2bf(f.z); o[3] = (short)f2bf(f.w);
        *(short4v*)(a.dst[seg] + (long)off * 4) = o;
    }
}

// ---------------------------------------------------------------------------
// Fold affine rel-pos MLP: W5[d][0..3]=Weff, W5[d][4]=beff  (fp32, [64][8])
// ---------------------------------------------------------------------------
__global__ void prep_w5(const float* __restrict__ w1, const float* __restrict__ b1,
                        const float* __restrict__ w2, const float* __restrict__ b2,
                        float* __restrict__ W5) {
    int d = threadIdx.x;  // 64 threads
    float a0=0.f,a1=0.f,a2=0.f,a3=0.f,ab=0.f;
    for (int e=0;e<64;++e) {
        float w = w2[d*64+e];
        a0 = fmaf(w, w1[e*4+0], a0);
        a1 = fmaf(w, w1[e*4+1], a1);
        a2 = fmaf(w, w1[e*4+2], a2);
        a3 = fmaf(w, w1[e*4+3], a3);
        ab = fmaf(w, b1[e], ab);
    }
    W5[d*8+0]=a0; W5[d*8+1]=a1; W5[d*8+2]=a2; W5[d*8+3]=a3;
    W5[d*8+4]=ab + b2[d];
    W5[d*8+5]=0.f; W5[d*8+6]=0.f; W5[d*8+7]=0.f;
}

// ---------------------------------------------------------------------------
// 128x64-tile MFMA GEMM (BK=64, 16 MFMA/iter/wave, register prefetch).
// MODE_QKV: N=1536 merged q/k/v (n0>=1024 -> V^T transpose epilogue).
// MODE_FFN1: bias + relu -> bf16.
// ---------------------------------------------------------------------------
enum { MODE_QKV=0, MODE_FFN1=1, MODE_FC=2, MODE_FFN2=3 };

template<int MODE>
__global__ __launch_bounds__(256,2)
void gemm128(const u16* __restrict__ A, int lda,
             const u16* __restrict__ B, int ldb,
             const float* __restrict__ biasf,
             void* __restrict__ outp, void* __restrict__ outp2,
             int K)
{
    int m0 = blockIdx.x * 128, n0 = blockIdx.y * 64;
    __shared__ __align__(16) u16 As[128*72];
    __shared__ __align__(16) u16 Bs[64*72];
    int tid = threadIdx.x;
    int lane = tid & 63, wave = tid >> 6;
    int wm = (wave >> 1) * 64, wn = (wave & 1) * 32;
    int mrow = lane & 15, quad = lane >> 4;
    floatx4 zz = {0.f,0.f,0.f,0.f};
    floatx4 acc[4][2];
    #pragma unroll
    for (int i=0;i<4;++i) { acc[i][0]=zz; acc[i][1]=zz; }

    int rA = tid >> 1, cA = (tid & 1) * 32;
    int rB = tid >> 2, cB = (tid & 3) * 16;
    const u16* pa = A + (long)(m0 + rA) * lda + cA;
    const u16* pb = B + (long)(n0 + rB) * ldb + cB;
    u16* asp = &As[rA*72 + cA];
    u16* bsp = &Bs[rB*72 + cB];

    short8 ra[4], rb[2];
    #pragma unroll
    for (int i=0;i<4;++i) ra[i] = *(const short8*)(pa + 8*i);
    #pragma unroll
    for (int i=0;i<2;++i) rb[i] = *(const short8*)(pb + 8*i);

    for (int k0 = 0; k0 < K; k0 += 64) {
        #pragma unroll
        for (int i=0;i<4;++i) *(short8*)(asp + 8*i) = ra[i];
        #pragma unroll
        for (int i=0;i<2;++i) *(short8*)(bsp + 8*i) = rb[i];
        __syncthreads();
        if (k0 + 64 < K) {
            int kn = k0 + 64;
            #pragma unroll
            for (int i=0;i<4;++i) ra[i] = *(const short8*)(pa + kn + 8*i);
            #pragma unroll
            for (int i=0;i<2;++i) rb[i] = *(const short8*)(pb + kn + 8*i);
        }
        #pragma unroll
        for (int s=0; s<2; ++s) {
            int qo = s*32 + quad*8;
            short8 bf0 = *(const short8*)(&Bs[(wn + mrow)*72 + qo]);
            short8 bf1 = *(const short8*)(&Bs[(wn + 16 + mrow)*72 + qo]);
            #pragma unroll
            for (int mt=0; mt<4; ++mt) {
                short8 af = *(const short8*)(&As[(wm + mt*16 + mrow)*72 + qo]);
                acc[mt][0] = __builtin_amdgcn_mfma_f32_16x16x32_bf16(af, bf0, acc[mt][0], 0,0,0);
                acc[mt][1] = __builtin_amdgcn_mfma_f32_16x16x32_bf16(af, bf1, acc[mt][1], 0,0,0);
            }
        }
        __syncthreads();
    }

    if constexpr (MODE == MODE_QKV) {
        if (n0 >= 1024) {
            __shared__ __align__(16) float Cs[128][65];
            #pragma unroll
            for (int mt=0; mt<4; ++mt)
            #pragma unroll
            for (int nt=0; nt<2; ++nt)
            #pragma unroll
            for (int rr=0; rr<4; ++rr)
                Cs[wm + mt*16 + quad*4 + rr][wn + nt*16 + mrow] = acc[mt][nt][rr];
            __syncthreads();
            u16* vt = (u16*)outp2;
            int b = m0 >> 9, i0b = m0 & 511, hh = (n0 - 1024) >> 6;
            #pragma unroll
            for (int t=0;t<32;++t) {
                int flat = tid + t*256;
                int d = flat >> 7, il = flat & 127;
                vt[(((long)(b*8 + hh)*64 + d) << 9) + i0b + il] = f2bf(Cs[il][d]);
            }
        } else {
            #pragma unroll
            for (int mt=0; mt<4; ++mt)
            #pragma unroll
            for (int nt=0; nt<2; ++nt)
            #pragma unroll
            for (int rr=0; rr<4; ++rr) {
                int mm = m0 + wm + mt*16 + quad*4 + rr;
                int nn = n0 + wn + nt*16 + mrow;
                int b = mm >> 9, i = mm & 511;
                int sel = nn >> 9, hh = (nn >> 6) & 7, d = nn & 63;
                ((u16*)outp)[(long)sel*1048576 +
                             (((long)(b*8 + hh)*512 + i) << 6) + d]
                    = f2bf(acc[mt][nt][rr]);
            }
        }
    } else {  // MODE_FFN1
        #pragma unroll
        for (int mt=0; mt<4; ++mt)
        #pragma unroll
        for (int nt=0; nt<2; ++nt)
        #pragma unroll
        for (int rr=0; rr<4; ++rr) {
            int mm = m0 + wm + mt*16 + quad*4 + rr;
            int nn = n0 + wn + nt*16 + mrow;
            float t = acc[mt][nt][rr] + biasf[nn];
            ((u16*)outp)[(long)mm*2048 + nn] = f2bf(t > 0.f ? t : 0.f);
        }
    }
}

// ---------------------------------------------------------------------------
// 64x64-tile MFMA GEMM with split-K (blockIdx.z): MODE_FC / MODE_FFN2.
// ---------------------------------------------------------------------------
template<int MODE>
__global__ __launch_bounds__(256,2)
void gemm64(const u16* __restrict__ A, int lda,
            const u16* __restrict__ B, int ldb,
            const float* __restrict__ biasf,
            const float* __restrict__ resf,
            const u16* __restrict__ resb,
            void* __restrict__ outp, void* __restrict__ outp2,
            int K)
{
    int bz = blockIdx.z;
    int m0 = blockIdx.x * 64, n0 = blockIdx.y * 64;
    __shared__ __align__(16) u16 As[64*72];
    __shared__ __align__(16) u16 Bs[64*72];
    int tid = threadIdx.x;
    int lane = tid & 63, wave = tid >> 6;
    int wm = (wave >> 1) * 32, wn = (wave & 1) * 32;
    int mrow = lane & 15, quad = lane >> 4;
    floatx4 zz = {0.f,0.f,0.f,0.f};
    floatx4 acc[2][2];
    acc[0][0]=zz; acc[0][1]=zz; acc[1][0]=zz; acc[1][1]=zz;
    int r = tid >> 3, c8 = (tid & 7) * 8;
    int koff = bz * K;
    const u16* pa = A + (long)(m0 + r) * lda + koff + c8;
    const u16* pb = B + (long)(n0 + r) * ldb + koff + c8;
    u16* asp = &As[r*72 + c8];
    u16* bsp = &Bs[r*72 + c8];
    const u16* a0p = &As[(wm + mrow)*72];
    const u16* a1p = &As[(wm + 16 + mrow)*72];
    const u16* b0p = &Bs[(wn + mrow)*72];
    const u16* b1p = &Bs[(wn + 16 + mrow)*72];
    short8 ra0 = *(const short8*)(pa);
    short8 ra1 = *(const short8*)(pa + 32*lda);
    short8 rb0 = *(const short8*)(pb);
    short8 rb1 = *(const short8*)(pb + 32*ldb);
    for (int k0 = 0; k0 < K; k0 += 64) {
        *(short8*)asp           = ra0;
        *(short8*)(asp + 32*72) = ra1;
        *(short8*)bsp           = rb0;
        *(short8*)(bsp + 32*72) = rb1;
        __syncthreads();
        if (k0 + 64 < K) {
            int kn = k0 + 64;
            ra0 = *(const short8*)(pa + kn);
            ra1 = *(const short8*)(pa + kn + 32*lda);
            rb0 = *(const short8*)(pb + kn);
            rb1 = *(const short8*)(pb + kn + 32*ldb);
        }
        #pragma unroll
        for (int s=0; s<2; ++s) {
            int qo = s*32 + quad*8;
            short8 af0 = *(const short8*)(a0p + qo);
            short8 af1 = *(const short8*)(a1p + qo);
            short8 bf0 = *(const short8*)(b0p + qo);
            short8 bf1 = *(const short8*)(b1p + qo);
            acc[0][0] = __builtin_amdgcn_mfma_f32_16x16x32_bf16(af0, bf0, acc[0][0], 0,0,0);
            acc[0][1] = __builtin_amdgcn_mfma_f32_16x16x32_bf16(af0, bf1, acc[0][1], 0,0,0);
            acc[1][0] = __builtin_amdgcn_mfma_f32_16x16x32_bf16(af1, bf0, acc[1][0], 0,0,0);
            acc[1][1] = __builtin_amdgcn_mfma_f32_16x16x32_bf16(af1, bf1, acc[1][1], 0,0,0);
        }
        __syncthreads();
    }
    #pragma unroll
    for (int im=0; im<2; ++im)
    #pragma unroll
    for (int in=0; in<2; ++in)
    #pragma unroll
    for (int rr=0; rr<4; ++rr) {
        int mm = m0 + wm + im*16 + quad*4 + rr;
        int nn = n0 + wn + in*16 + mrow;
        float v = acc[im][in][rr];
        float* OP = (float*)(bz ? outp2 : outp);
        if constexpr (MODE == MODE_FC) {
            OP[(long)mm*512 + nn] = bz ? v : v + resf[(long)mm*512 + nn];
        } else { // MODE_FFN2
            OP[(long)mm*512 + nn] =
                bz ? v : v + biasf[nn] + bf2f(resb[(long)mm*512 + nn]);
        }
    }
}

// ---------------------------------------------------------------------------
// MFMA attention scores + softmax + fused P@V.
// s[j,i] = (1/8)[ sum_p pos[j,i,p]*G_p[j,i] + G_4[j,i] ],
// G_p[j,i] = sum_d (k[j,d]*W5[d][p]) * q[i,d].
// After softmax, normalized P is packed bf16 into the front of S (in-place),
// then P@V runs on ds_read_b128 fragments with two independent MFMA chains.
// ---------------------------------------------------------------------------
__global__ __launch_bounds__(256,2)
void attn_scores(const u16* __restrict__ qws, const u16* __restrict__ kws,
                 const float* __restrict__ posf, const float* __restrict__ W5g,
                 const u16* __restrict__ vtws, u16* __restrict__ aows,
                 float* __restrict__ attn_of)
{
    int jt = blockIdx.x, h = blockIdx.y, b = blockIdx.z;
    int j0 = jt * 16;
    int bh = b*8 + h;
    const u16* qb = qws + (long)bh * 512 * 64;
    const u16* kb = kws + (long)bh * 512 * 64;
    __shared__ __align__(16) float W5s[512];
    __shared__ __align__(16) float S[16*516];
    __shared__ __align__(16) float redm[16][17];
    __shared__ __align__(16) float reds[16][17];
    __shared__ float rinvs[16];
    int tid = threadIdx.x;
    int lane = tid & 63, wave = tid >> 6;
    int m = lane & 15, quad = lane >> 4;
    if (tid < 64) {
        #pragma unroll
        for (int p=0;p<8;++p) W5s[tid*8+p] = W5g[tid*8+p];
    }
    __syncthreads();
    short8 af[5][2];
    #pragma unroll
    for (int s=0; s<2; ++s) {
        short8 kf = *(const short8*)(kb + (long)(j0 + m)*64 + s*32 + quad*8);
        float kv[8];
        #pragma unroll
        for (int e=0;e<8;++e) kv[e] = bf2f((u16)kf[e]);
        int db = s*32 + quad*8;
        #pragma unroll
        for (int p=0;p<5;++p) {
            short8 t;
            #pragma unroll
            for (int e=0;e<8;++e) t[e] = (short)f2bf(kv[e] * W5s[(db+e)*8 + p]);
            af[p][s] = t;
        }
    }
    floatx4 zz = {0.f,0.f,0.f,0.f};
    for (int it = wave*8; it < wave*8 + 8; ++it) {
        int i0 = it * 16;
        short8 bf0 = *(const short8*)(qb + (long)(i0 + m)*64 + quad*8);
        short8 bf1 = *(const short8*)(qb + (long)(i0 + m)*64 + 32 + quad*8);
        floatx4 a0 = __builtin_amdgcn_mfma_f32_16x16x32_bf16(af[0][0], bf0, zz, 0,0,0);
        floatx4 a1 = __builtin_amdgcn_mfma_f32_16x16x32_bf16(af[1][0], bf0, zz, 0,0,0);
        floatx4 a2 = __builtin_amdgcn_mfma_f32_16x16x32_bf16(af[2][0], bf0, zz, 0,0,0);
        floatx4 a3 = __builtin_amdgcn_mfma_f32_16x16x32_bf16(af[3][0], bf0, zz, 0,0,0);
        floatx4 a4 = __builtin_amdgcn_mfma_f32_16x16x32_bf16(af[4][0], bf0, zz, 0,0,0);
        a0 = __builtin_amdgcn_mfma_f32_16x16x32_bf16(af[0][1], bf1, a0, 0,0,0);
        a1 = __builtin_amdgcn_mfma_f32_16x16x32_bf16(af[1][1], bf1, a1, 0,0,0);
        a2 = __builtin_amdgcn_mfma_f32_16x16x32_bf16(af[2][1], bf1, a2, 0,0,0);
        a3 = __builtin_amdgcn_mfma_f32_16x16x32_bf16(af[3][1], bf1, a3, 0,0,0);
        a4 = __builtin_amdgcn_mfma_f32_16x16x32_bf16(af[4][1], bf1, a4, 0,0,0);
        long pb0 = (((long)(b*512 + j0 + quad*4))*512 + i0 + m) * 4;
        #pragma unroll
        for (int rr=0; rr<4; ++rr) {
            float4 pp = *(const float4*)&posf[pb0 + (long)rr*2048];
            float sv = a4[rr];
            sv = fmaf(pp.x, a0[rr], sv);
            sv = fmaf(pp.y, a1[rr], sv);
            sv = fmaf(pp.z, a2[rr], sv);
            sv = fmaf(pp.w, a3[rr], sv);
            S[(quad*4 + rr)*516 + i0 + m] = sv * 0.125f;
        }
    }
    __syncthreads();
    // softmax over i (512) per j-row
    int j = tid >> 4, sub = tid & 15;
    float mx = -1e30f;
    for (int t=0;t<32;++t) mx = fmaxf(mx, S[j*516 + sub + t*16]);
    redm[j][sub] = mx;
    __syncthreads();
    float mval = redm[j][0];
    #pragma unroll
    for (int p=1;p<16;++p) mval = fmaxf(mval, redm[j][p]);
    float sum = 0.f;
    for (int t=0;t<32;++t) {
        int i = sub + t*16;
        float e = __expf(S[j*516 + i] - mval);
        S[j*516 + i] = e;
        sum += e;
    }
    reds[j][sub] = sum;
    __syncthreads();
    float tot = 0.f;
    #pragma unroll
    for (int p=0;p<16;++p) tot += reds[j][p];
    if (sub == 0) rinvs[j] = 1.0f / tot;
    __syncthreads();
    // Phase A: buffer this thread's 16 float2 pairs in registers
    float2 tmp[16];
    #pragma unroll
    for (int t=0;t<16;++t) {
        int idx = (tid + t*256) * 2;
        tmp[t] = *(const float2*)&S[(idx >> 9)*516 + (idx & 511)];
    }
    __syncthreads();
    // Phase B: write normalized fp32 attn (output 1) + packed bf16 P into
    // the front 256 words of each S row (in-place reuse).
    long rowbase = ((long)bh * 512 + j0) * 512;
    #pragma unroll
    for (int t=0;t<16;++t) {
        int idx = (tid + t*256) * 2;
        int jj = idx >> 9, i = idx & 511;
        float ri = rinvs[jj];
        float v0 = tmp[t].x * ri, v1 = tmp[t].y * ri;
        float2 f2; f2.x = v0; f2.y = v1;
        *(float2*)&attn_of[rowbase + (long)jj*512 + i] = f2;
        ((u32*)S)[jj*516 + (i >> 1)] = (u32)f2bf(v0) | ((u32)f2bf(v1) << 16);
    }
    __syncthreads();
    // Phase C: P@V from packed bf16 LDS, two independent MFMA chains.
    const u16* Sb = (const u16*)S;          // row stride 1032 u16
    int dd = wave*16 + m;
    const u16* vb = vtws + (long)bh * 64 * 512 + (long)dd * 512;
    floatx4 o0 = zz, o1 = zz;
    #pragma unroll
    for (int kk = 0; kk < 8; ++kk) {
        short8 pa0 = *(const short8*)(Sb + m*1032 + kk*32 + quad*8);
        short8 pa1 = *(const short8*)(Sb + m*1032 + (kk+8)*32 + quad*8);
        short8 vb0 = *(const short8*)(vb + kk*32 + quad*8);
        short8 vb1 = *(const short8*)(vb + (kk+8)*32 + quad*8);
        o0 = __builtin_amdgcn_mfma_f32_16x16x32_bf16(pa0, vb0, o0, 0,0,0);
        o1 = __builtin_amdgcn_mfma_f32_16x16x32_bf16(pa1, vb1, o1, 0,0,0);
    }
    #pragma unroll
    for (int rr=0; rr<4; ++rr) {
        int jj = quad*4 + rr;
        aows[((long)(b*512 + j0 + jj))*512 + h*64 + dd] = f2bf(o0[rr] + o1[rr]);
    }
}

// ---------------------------------------------------------------------------
// LayerNorm over 512 cols, fp32 in (x [+ x2 partial]); bf16/fp32 out.
// ---------------------------------------------------------------------------
__global__ __launch_bounds__(256)
void ln_kernel(const float* __restrict__ x, const float* __restrict__ x2,
               const float* __restrict__ g, const float* __restrict__ bb,
               u16* __restrict__ outb, float* __restrict__ outf)
{
    int row = blockIdx.x, tid = threadIdx.x;
    const float* xr = x + (long)row * 512;
    float v0 = xr[tid*2], v1 = xr[tid*2+1];
    if (x2) {
        const float* x2r = x2 + (long)row * 512;
        v0 += x2r[tid*2];
        v1 += x2r[tid*2+1];
    }
    __shared__ float r1[256], r2[256];
    r1[tid] = v0 + v1;
    r2[tid] = v0*v0 + v1*v1;
    __syncthreads();
    for (int sft=128; sft>0; sft>>=1) {
        if (tid < sft) { r1[tid] += r1[tid+sft]; r2[tid] += r2[tid+sft]; }
        __syncthreads();
    }
    float mu = r1[0] * (1.0f/512.0f);
    float var = r2[0] * (1.0f/512.0f) - mu*mu;
    float rs = rsqrtf(var + 1e-6f);
    float y0 = fmaf((v0-mu)*rs, g[tid*2],   bb[tid*2]);
    float y1 = fmaf((v1-mu)*rs, g[tid*2+1], bb[tid*2+1]);
    if (outf) {
        float2 f2; f2.x = y0; f2.y = y1;
        *(float2*)&outf[(long)row*512 + tid*2] = f2;
    }
    if (outb) {
        ((u32*)outb)[row*256 + tid] = (u32)f2bf(y0) | ((u32)f2bf(y1) << 16);
    }
}

// ---------------------------------------------------------------------------
// ws layout (MB), peak 22.0 + 4KB:
//   0-2     enc_c bf16       -> aows bf16 (attn epilogue) -> dead after FC
//   2-6     p1fc fp32 (FC partial); 2-10 hws bf16 after LN1
//   10-10.5 wq_c; 10.5-11 wk_c; 11-11.5 wv_c; 11.5-12 wfc_c
//   12-14   fw1_c            -> [10-14) = p1f2 fp32 after FFN1
//   14-16   fw2_c
//   16-18   qws;  18-20 kws  -> ln1ws bf16 at 18 after attn
//   20-22   vtws             [live through attn (fused PV)]
//   22+     W5 (2KB)
// res (4MB fp32) lives in d_out's output-0 slab (LN in-place).
// pos is read fp32 directly from d_in[1] (no canonical copy).
// ---------------------------------------------------------------------------
extern "C" void kernel_launch(void* const* d_in, const int* in_sizes, int n_in,
                              void* d_out, int out_size, void* d_ws, size_t ws_size,
                              hipStream_t stream)
{
    const float* enc_f  = (const float*)d_in[0];
    const float* pos_f  = (const float*)d_in[1];
    const float* rp_w1  = (const float*)d_in[6];
    const float* rp_b1  = (const float*)d_in[7];
    const float* rp_w2  = (const float*)d_in[8];
    const float* rp_b2  = (const float*)d_in[9];
    const float* ln1_g  = (const float*)d_in[10];
    const float* ln1_b  = (const float*)d_in[11];
    const float* ln2_g  = (const float*)d_in[12];
    const float* ln2_b  = (const float*)d_in[13];
    const float* ffn_b1 = (const float*)d_in[15];
    const float* ffn_b2 = (const float*)d_in[17];

    char* ws = (char*)d_ws;
    const size_t MB = 1048576ul;
    u16* enc_c = (u16*)(ws + 0);
    u16* wq_c  = (u16*)(ws + 10*MB);
    u16* wk_c  = (u16*)(ws + 10*MB + 524288);
    u16* wv_c  = (u16*)(ws + 11*MB);
    u16* wfc_c = (u16*)(ws + 11*MB + 524288);
    u16* fw1_c = (u16*)(ws + 12*MB);
    u16* fw2_c = (u16*)(ws + 14*MB);
    u16* qws   = (u16*)(ws + 16*MB);
    u16* kws   = (u16*)(ws + 18*MB);
    u16* vtws  = (u16*)(ws + 20*MB);
    u16* aows  = (u16*)(ws + 0);          // alias enc_c (dead after QKV)
    u16* hws   = (u16*)(ws + 2*MB);
    u16* ln1ws = (u16*)(ws + 18*MB);      // alias kws (dead after attn)
    float* p1fc = (float*)(ws + 2*MB);    // FC partial
    float* p1f2 = (float*)(ws + 10*MB);   // FFN2 partial (weights dead)
    float* W5   = (float*)(ws + 22*MB);

    float* out0_f = (float*)d_out;
    float* attn_f = out0_f + 1048576;
    float* res    = out0_f;

    dim3 blk(256);

    Cvt7 ca;
    const float* srcs[7] = { enc_f, (const float*)d_in[2], (const float*)d_in[3],
                             (const float*)d_in[4], (const float*)d_in[5],
                             (const float*)d_in[14], (const float*)d_in[16] };
    u16* dsts[7] = { enc_c, wq_c, wk_c, wv_c, wfc_c, fw1_c, fw2_c };
    int sizes4[7] = { 262144, 65536, 65536, 65536, 65536, 262144, 262144 };
    int pre = 0;
    for (int i = 0; i < 7; ++i) {
        ca.src[i] = srcs[i]; ca.dst[i] = dsts[i]; ca.pre[i] = pre;
        pre += sizes4[i];
    }
    ca.pre[7] = pre;
    convert7<<<dim3(4096), blk, 0, stream>>>(ca);

    prep_w5<<<dim3(1), dim3(64), 0, stream>>>(rp_w1, rp_b1, rp_w2, rp_b2, W5);

    // merged Q+K+V projection (128x64 tiles): M=2048, N=1536, K=512
    gemm128<MODE_QKV><<<dim3(16,24,1), blk, 0, stream>>>(
        enc_c, 512, wq_c, 512, nullptr, (void*)qws, (void*)vtws, 512);

    // scores + softmax + fused P@V -> attn (output 1) + aows
    attn_scores<<<dim3(32,8,4), blk, 0, stream>>>(
        qws, kws, pos_f, W5, vtws, aows, attn_f);

    // fc + residual, split-K=2; LN1 reduces partials
    gemm64<MODE_FC><<<dim3(32,8,2), blk, 0, stream>>>(
        aows, 512, wfc_c, 512, nullptr, enc_f, nullptr,
        (void*)res, (void*)p1fc, 256);
    ln_kernel<<<dim3(2048), blk, 0, stream>>>(res, p1fc, ln1_g, ln1_b, ln1ws, nullptr);

    // FFN1 (128x64 tiles): M=2048, N=2048, K=512
    gemm128<MODE_FFN1><<<dim3(16,32,1), blk, 0, stream>>>(
        ln1ws, 512, fw1_c, 512, ffn_b1, (void*)hws, nullptr, 512);

    // FFN2 split-K=2; LN2 reduces -> output 0
    gemm64<MODE_FFN2><<<dim3(32,8,2), blk, 0, stream>>>(
        hws, 2048, fw2_c, 2048, ffn_b2, nullptr, ln1ws,
        (void*)res, (void*)p1f2, 1024);
    ln_kernel<<<dim3(2048), blk, 0, stream>>>(res, p1f2, ln2_g, ln2_b, nullptr, out0_f);
}